// Round 1
// baseline (213.456 us; speedup 1.0000x reference)
//
#include <hip/hip_runtime.h>
#include <stdint.h>
#include <stddef.h>

// ---------------- problem constants ----------------
// B=2048, F0=39, D=16, layers 128/128/128, xk halves to 64 after each layer.
// z[b,s,d] = sum_{h,k} x0[b,h,d]*xk[b,k,d]*W[h,k,s]  -> GEMM M=(b,d)=32768, N=s=128,
// K=(h,k) with k padded 39->64 (layer0) so K = 39*64 = 2496 for ALL layers.
#define F0N    39
#define DN     16
#define SN     128
#define KPAD   64
#define NCHUNK 78                      // 2496 / 32
#define WROW   40                      // bf16 per staged-W row: 32 + 8 pad (80B, 16B-aligned)
#define XROW   72                      // bf16 per X0/XK row: 64 + 8 pad (144B, 16B-aligned)
#define CHUNK_ELEMS (SN * WROW)        // 5120 bf16 = 10240 B per staged chunk
#define PER_LAYER_ELEMS (NCHUNK * CHUNK_ELEMS)

typedef __attribute__((ext_vector_type(8))) short short8;   // 8 bf16 (4 VGPRs) MFMA operand
typedef __attribute__((ext_vector_type(4))) float floatx4;  // MFMA accumulator
typedef __attribute__((ext_vector_type(4))) uint32_t uint4v;

__device__ __forceinline__ uint16_t f2bf(float f) {         // RNE f32->bf16
  uint32_t u = __float_as_uint(f);
  u += 0x7fffu + ((u >> 16) & 1u);
  return (uint16_t)(u >> 16);
}
__device__ __forceinline__ float bf2f(uint16_t b) {
  return __uint_as_float(((uint32_t)b) << 16);
}

// async global->LDS, 16B per lane. LDS offset = low 32 bits of generic pointer
// (addrspacecast generic->local is a truncation on gfx9xx).
__device__ __forceinline__ void load16_lds(const void* g, void* l) {
  __builtin_amdgcn_global_load_lds(
      (__attribute__((address_space(1))) uint32_t*)(uintptr_t)g,
      (__attribute__((address_space(3))) uint32_t*)(uint32_t)(uintptr_t)l,
      16, 0, 0);
}

// ---------------- pre-pass: W fp32 -> blocked bf16 ----------------
// Wblk[L][chunk = kidx>>5][n][kidx&31], rows padded to WROW=40 bf16.
// kidx = h*64 + k ; k >= fk zero-filled. Pad cols 32..39 never read.
__global__ __launch_bounds__(256) void cin_prepass(
    const float* __restrict__ w0, const float* __restrict__ w1,
    const float* __restrict__ w2, uint16_t* __restrict__ wout) {
  int idx = blockIdx.x * 256 + threadIdx.x;      // grid sized exactly: 3*319488 threads
  const int per_layer = KPAD * F0N * SN;         // 319488
  int L = (idx >= 2 * per_layer) ? 2 : ((idx >= per_layer) ? 1 : 0);
  int r = idx - L * per_layer;
  int kidx = r >> 7;
  int n = r & 127;
  int h = kidx >> 6, k = kidx & 63;
  const float* W = (L == 0) ? w0 : ((L == 1) ? w1 : w2);
  int fk = (L == 0) ? 39 : 64;
  float v = (k < fk) ? W[(h * fk + k) * SN + n] : 0.0f;
  size_t off = (size_t)L * PER_LAYER_ELEMS + (size_t)(kidx >> 5) * CHUNK_ELEMS
             + (size_t)n * WROW + (kidx & 31);
  wout[off] = f2bf(v);
}

// ---------------- fused main kernel ----------------
// 256 workgroups x 256 threads. Block owns 128 rows m = b_local*16 + d
// (8 batches, all 16 d) -> xk handoff and sum_d are block-local.
// Wave w: wm=(w&1)*64, wn=(w>>1)*64 ; 4x4 accs of 16x16x32 bf16 MFMA.
__global__ __launch_bounds__(256) void cin_main(
    const float* __restrict__ x,       // (2048, 39, 16) fp32
    const float* __restrict__ bias0, const float* __restrict__ bias1,
    const float* __restrict__ bias2,
    const uint16_t* __restrict__ wblk, // blocked bf16 weights in d_ws
    float* __restrict__ out) {         // (2048, 256) fp32

  __shared__ __align__(16) uint16_t X0[128 * XROW];     // bf16 x0[m][h], h<39, rest 0
  __shared__ __align__(16) uint16_t XK[128 * XROW];     // bf16 xk[m][k], k<64
  __shared__ __align__(16) uint16_t WS[2][CHUNK_ELEMS]; // double-buffered W chunk

  const int tid  = threadIdx.x;
  const int lane = tid & 63;
  const int wave = tid >> 6;
  const int l16  = lane & 15;
  const int quad = lane >> 4;
  const int wm = (wave & 1) * 64;
  const int wn = (wave >> 1) * 64;
  const int bbase = blockIdx.x * 8;

  // zero X0 (incl. pads; layer-0 xk cols 39..63 must be 0)
  {
    uint32_t* p = (uint32_t*)X0;
#pragma unroll
    for (int i = 0; i < 18; i++) p[tid + 256 * i] = 0u;   // 18*256*4 = 18432 B
  }
  __syncthreads();

  // fill X0[m = bl*16+d][h] = bf16(x[bbase+bl][h][d])  (coalesced over d)
  {
    const int d = tid & 15, t = tid >> 4;
#pragma unroll 4
    for (int j = 0; j < 20; j++) {
      int p = j * 16 + t;
      if (p < 8 * F0N) {
        int bl = p / F0N;
        int h  = p - bl * F0N;
        float v = x[(size_t)(bbase + bl) * (F0N * DN) + h * DN + d];
        X0[(bl * 16 + d) * XROW + h] = f2bf(v);
      }
    }
  }

  // loop-invariant lane offsets (uint16 units)
  int x0row[4], akoff[4], boff[4];
#pragma unroll
  for (int i = 0; i < 4; i++) {
    x0row[i] = (wm + i * 16 + l16) * XROW;      // scalar h-reads: conflict-free
    akoff[i] = x0row[i] + quad * 8;             // xk vec reads: 16B-aligned, ~2-way
    boff[i]  = (wn + i * 16 + l16) * WROW + quad * 8;  // W reads: 16B-aligned, 2-way
  }

  // prologue: stage layer-0 chunk 0 into WS[0]
  {
    const uint16_t* g = wblk;
#pragma unroll
    for (int it = 0; it < 3; it++) {
      int i = tid + it * 256;
      if (i < 640) load16_lds(g + i * 8, ((uint16_t*)WS[0]) + i * 8);
    }
  }

#pragma unroll 1
  for (int L = 0; L < 3; L++) {
    const uint16_t* xk16 = (L == 0) ? X0 : XK;
    floatx4 acc[4][4] = {};

#pragma unroll 1
    for (int c = 0; c < NCHUNK; c++) {
      // single barrier per chunk: drains stage(c) (vmcnt) + all LDS r/w, syncs waves.
      __syncthreads();

      // issue next stage (overlaps with compute below, drained at next barrier)
      {
        const uint16_t* g = nullptr;
        uint16_t* dst = nullptr;
        if (c + 1 < NCHUNK) {
          g = wblk + (size_t)L * PER_LAYER_ELEMS + (size_t)(c + 1) * CHUNK_ELEMS;
          dst = (uint16_t*)WS[(c + 1) & 1];
        } else if (L < 2) {   // prologue for next layer chunk 0 (WS[0] free: last read c=76)
          g = wblk + (size_t)(L + 1) * PER_LAYER_ELEMS;
          dst = (uint16_t*)WS[0];
        }
        if (g) {
#pragma unroll
          for (int it = 0; it < 3; it++) {
            int i = tid + it * 256;
            if (i < 640) load16_lds(g + i * 8, dst + i * 8);
          }
        }
      }

      const int h  = c >> 1;            // chunk -> (h, k-half)
      const int k2 = (c & 1) << 5;
      const uint16_t* wsrc = (const uint16_t*)WS[c & 1];

      float xs[4];
#pragma unroll
      for (int mi = 0; mi < 4; mi++) xs[mi] = bf2f(X0[x0row[mi] + h]);

      short8 bfr[4];
#pragma unroll
      for (int ni = 0; ni < 4; ni++)
        bfr[ni] = *(const short8*)(wsrc + boff[ni]);   // B[k=quad*8+j][n=l16]

      short8 afr[4];
#pragma unroll
      for (int mi = 0; mi < 4; mi++) {
        uint4v w = *(const uint4v*)(xk16 + akoff[mi] + k2);  // 8 bf16 of xk
        const float s = xs[mi];
        uint32_t rr[4];
#pragma unroll
        for (int t = 0; t < 4; t++) {
          uint32_t wv = (t == 0) ? w.x : (t == 1) ? w.y : (t == 2) ? w.z : w.w;
          float lo = __uint_as_float(wv << 16) * s;          // even k element
          float hi = __uint_as_float(wv & 0xffff0000u) * s;  // odd k element
          // pack truncated bf16 pair: D = [lo>>16, hi>>16] via v_perm_b32
          rr[t] = __builtin_amdgcn_perm(__float_as_uint(hi), __float_as_uint(lo),
                                        0x07060302u);
        }
        uint4v av = {rr[0], rr[1], rr[2], rr[3]};
        afr[mi] = __builtin_bit_cast(short8, av);            // A[m=l16][k=quad*8+j]
      }

#pragma unroll
      for (int mi = 0; mi < 4; mi++)
#pragma unroll
        for (int ni = 0; ni < 4; ni++)
          acc[mi][ni] = __builtin_amdgcn_mfma_f32_16x16x32_bf16(
              afr[mi], bfr[ni], acc[mi][ni], 0, 0, 0);
    } // chunk loop

    __syncthreads();  // all reads done before XK overwrite / before next-layer staging use

    // ---- epilogue: bias + relu ; sum_d -> out ; xk handoff ----
    const float* bl = (L == 0) ? bias0 : ((L == 1) ? bias1 : bias2);
    float bv[4];
#pragma unroll
    for (int ni = 0; ni < 4; ni++) bv[ni] = bl[wn + ni * 16 + l16];

    // C/D layout: D[m = quad*4+reg][n = l16] (m89/m91-verified).
    // Rows of one mi-block = the 16 d's of b_local = wm/16 + mi.
    if (L == 2 || wn == 64) {   // direct-output columns
#pragma unroll
      for (int mi = 0; mi < 4; mi++) {
        const int blocal = (wm >> 4) + mi;
#pragma unroll
        for (int ni = 0; ni < 4; ni++) {
          float sacc = 0.f;
#pragma unroll
          for (int r = 0; r < 4; r++) sacc += fmaxf(acc[mi][ni][r] + bv[ni], 0.f);
          sacc += __shfl_xor(sacc, 16);   // reduce over quad -> sum over all 16 d
          sacc += __shfl_xor(sacc, 32);
          if (quad == 0) {
            // concat map: L0 s64:128 -> 0:64 ; L1 s64:128 -> 64:128 ; L2 s -> 128:256
            int col = (L == 2) ? (128 + wn + ni * 16 + l16) : (L * 64 + ni * 16 + l16);
            out[(size_t)(bbase + blocal) * 256 + col] = sacc;
          }
        }
      }
    }
    if (L < 2 && wn == 0) {     // xk = relu(z)[:, :64]  (waves 0,1 cover all 128 m rows)
#pragma unroll
      for (int mi = 0; mi < 4; mi++)
#pragma unroll
        for (int ni = 0; ni < 4; ni++)
#pragma unroll
          for (int r = 0; r < 4; r++) {
            int m = wm + mi * 16 + quad * 4 + r;
            int k = ni * 16 + l16;
            float z = fmaxf(acc[mi][ni][r] + bv[ni], 0.f);
            XK[m * XROW + k] = f2bf(z);
          }
    }
    // next layer's first __syncthreads orders XK writes before formation reads
  } // layer loop
}

extern "C" void kernel_launch(void* const* d_in, const int* in_sizes, int n_in,
                              void* d_out, int out_size, void* d_ws, size_t ws_size,
                              hipStream_t stream) {
  (void)in_sizes; (void)n_in; (void)out_size; (void)ws_size;
  const float* x  = (const float*)d_in[0];
  const float* w0 = (const float*)d_in[1];
  const float* b0 = (const float*)d_in[2];
  const float* w1 = (const float*)d_in[3];
  const float* b1 = (const float*)d_in[4];
  const float* w2 = (const float*)d_in[5];
  const float* b2 = (const float*)d_in[6];
  uint16_t* wblk  = (uint16_t*)d_ws;   // needs 3*78*128*40*2 = 2,396,160 B

  // 3 * 319488 elements / 256 = 3744 blocks exactly
  cin_prepass<<<3744, 256, 0, stream>>>(w0, w1, w2, wblk);
  cin_main<<<256, 256, 0, stream>>>(x, b0, b1, b2, wblk, (float*)d_out);
}

// Round 3
// 186.536 us; speedup vs baseline: 1.1443x; 1.1443x over previous
//
#include <hip/hip_runtime.h>
#include <stdint.h>
#include <stddef.h>

// ---------------- problem constants ----------------
// B=2048, F0=39, D=16, layers 128/128/128, xk halves to 64 after each layer.
// GEMM view: M=(b,d), N=s=128, K=(h,k) padded to 39*64=2496 for all layers.
#define F0N    39
#define DN     16
#define SN     128
#define NCHUNK 78                      // 2496 / 32
#define WROW   40                      // bf16 per staged-W row: 32 + 8 pad (80B, 16B-aligned)
#define XROW   72                      // bf16 per X0/XK row: 64 + 8 pad (144B, 16B-aligned)
#define CHUNK_ELEMS (SN * WROW)        // 5120 bf16 = 10240 B per staged chunk
#define PER_LAYER_ELEMS (NCHUNK * CHUNK_ELEMS)
#define TOTCHUNK 234                   // 3 * 78

typedef __attribute__((ext_vector_type(8))) short short8;   // MFMA A/B operand
typedef __attribute__((ext_vector_type(4))) float floatx4;  // MFMA accumulator
typedef __attribute__((ext_vector_type(4))) uint32_t uint4v;

__device__ __forceinline__ uint16_t f2bf(float f) {         // RNE f32->bf16
  uint32_t u = __float_as_uint(f);
  u += 0x7fffu + ((u >> 16) & 1u);
  return (uint16_t)(u >> 16);
}
__device__ __forceinline__ float bf2f(uint16_t b) {
  return __uint_as_float(((uint32_t)b) << 16);
}

// async global->LDS, 16B per lane (wave-uniform base + lane*16 pattern)
__device__ __forceinline__ void load16_lds(const void* g, void* l) {
  __builtin_amdgcn_global_load_lds(
      (__attribute__((address_space(1))) uint32_t*)(uintptr_t)g,
      (__attribute__((address_space(3))) uint32_t*)(uint32_t)(uintptr_t)l,
      16, 0, 0);
}

// ---------------- pre-pass: W fp32 -> bf16, R1 [n][k] layout, LDS transpose ----------------
// One block per (L, chunk). Output chunk layout IDENTICAL to round-1 (verified):
//   wout[bc*CHUNK_ELEMS + n*WROW + k_in_chunk], k_in_chunk < 32; pad [32,40) unwritten/never read.
__global__ __launch_bounds__(256) void cin_prepass(
    const float* __restrict__ w0, const float* __restrict__ w1,
    const float* __restrict__ w2, uint16_t* __restrict__ wout) {
  __shared__ float T[32 * 132];               // [k_in_chunk][n], +4 pad floats per row
  const int bc = blockIdx.x;                  // 0..233
  const int L = bc / NCHUNK;
  const int c = bc - L * NCHUNK;
  const float* W = (L == 0) ? w0 : ((L == 1) ? w1 : w2);
  const int fk = (L == 0) ? 39 : 64;
  const int tid = threadIdx.x;

  // coalesced read: 32 k-rows of 128 fp32 (k padded to 64 per h)
  for (int e = tid; e < 4096; e += 256) {
    int kc = e >> 7, n = e & 127;
    int kidx = c * 32 + kc;
    int h = kidx >> 6, k = kidx & 63;
    float v = (k < fk) ? W[(h * fk + k) * SN + n] : 0.0f;
    T[kc * 132 + n] = v;
  }
  __syncthreads();
  // packed u32 writes in [n][k] order: row n gets 16 u32 (32 bf16)
  uint32_t* dst32 = (uint32_t*)(wout + (size_t)bc * CHUNK_ELEMS);
  for (int e = tid; e < 2048; e += 256) {
    int n = e >> 4, i = e & 15;                // k pair (2i, 2i+1)
    uint32_t lo = f2bf(T[(2 * i) * 132 + n]);
    uint32_t hi = f2bf(T[(2 * i + 1) * 132 + n]);
    dst32[n * (WROW / 2) + i] = lo | (hi << 16);
  }
}

// ---------------- fused main kernel ----------------
// 512 blocks x 256 threads (4 waves). Block owns 4 batches (M = 64 rows,
// m = bl*16 + d) -> d-sum and xk handoff block-local. 2 blocks/CU, 2 waves/SIMD.
// Wave tile: wm=(wave&1)*32, wn=(wave>>1)*64, acc 2x4. All data paths = round-1.
__global__ __launch_bounds__(256, 2) void cin_main(
    const float* __restrict__ x,       // (2048, 39, 16) fp32
    const float* __restrict__ bias0, const float* __restrict__ bias1,
    const float* __restrict__ bias2,
    const uint16_t* __restrict__ wblk, // blocked bf16 weights (d_ws)
    float* __restrict__ out) {         // (2048, 256) fp32

  __shared__ __align__(16) uint16_t X0[64 * XROW];      // bf16 x0[m][h], h<39, rest 0
  __shared__ __align__(16) uint16_t XK[64 * XROW];      // bf16 xk[m][k], k<64
  __shared__ __align__(16) uint16_t WS[2][CHUNK_ELEMS]; // double-buffered W chunk

  const int tid  = threadIdx.x;
  const int lane = tid & 63;
  const int wave = tid >> 6;
  const int l16  = lane & 15;
  const int quad = lane >> 4;
  const int wm = (wave & 1) * 32;
  const int wn = (wave >> 1) * 64;     // 0 or 64
  const int bbase = blockIdx.x * 4;
  const int mtb = wm >> 4;             // 0 or 2

  // zero X0 (incl. pads; layer-0 xk cols 39..63 must be 0): 64*72*2 = 9216 B
  {
    uint32_t* p = (uint32_t*)X0;
#pragma unroll
    for (int i = 0; i < 9; i++) p[tid + 256 * i] = 0u;
  }
  __syncthreads();

  // fill X0[m = bl*16+d][h] = bf16(x[bbase+bl][h][d])  (coalesced over e)
#pragma unroll
  for (int it = 0; it < 10; ++it) {
    int e = tid + it * 256;            // e = bl*624 + h*16 + d
    if (e < 4 * F0N * DN) {
      float v = x[(size_t)bbase * (F0N * DN) + e];
      int d = e & 15, p = e >> 4;
      int bl = p / F0N, h = p - bl * F0N;
      X0[(bl * 16 + d) * XROW + h] = f2bf(v);
    }
  }

  // loop-invariant lane offsets (uint16 units) — round-1 forms
  int x0row[2], akoff[2], boff[4];
#pragma unroll
  for (int i = 0; i < 2; i++) {
    x0row[i] = (wm + i * 16 + l16) * XROW;             // scalar h-reads
    akoff[i] = x0row[i] + quad * 8;                    // xk vec reads (+k2)
  }
#pragma unroll
  for (int i = 0; i < 4; i++)
    boff[i]  = (wn + i * 16 + l16) * WROW + quad * 8;  // W reads

  // prologue: stage layer-0 chunk 0 into WS[0] (640 x 16B lane-loads)
  {
    const uint16_t* g = wblk;
#pragma unroll
    for (int it = 0; it < 3; it++) {
      int i = tid + it * 256;
      if (i < 640) load16_lds(g + i * 8, ((uint16_t*)WS[0]) + i * 8);
    }
  }

#pragma unroll 1
  for (int L = 0; L < 3; L++) {
    const uint16_t* xk16 = (L == 0) ? X0 : XK;
    floatx4 acc[2][4] = {};

#pragma unroll 1
    for (int c = 0; c < NCHUNK; c++) {
      // single barrier per chunk: drains stage(c) (vmcnt) + all LDS r/w, syncs waves.
      __syncthreads();

      // issue next stage (overlaps with compute, drained at next barrier)
      {
        const uint16_t* g = nullptr;
        uint16_t* dst = nullptr;
        if (c + 1 < NCHUNK) {
          g = wblk + (size_t)L * PER_LAYER_ELEMS + (size_t)(c + 1) * CHUNK_ELEMS;
          dst = (uint16_t*)WS[(c + 1) & 1];
        } else if (L < 2) {   // prologue for next layer chunk 0 (WS[0] last read c=76)
          g = wblk + (size_t)(L + 1) * PER_LAYER_ELEMS;
          dst = (uint16_t*)WS[0];
        }
        if (g) {
#pragma unroll
          for (int it = 0; it < 3; it++) {
            int i = tid + it * 256;
            if (i < 640) load16_lds(g + i * 8, dst + i * 8);
          }
        }
      }

      const int h  = c >> 1;            // chunk -> (h, k-half)
      const int k2 = (c & 1) << 5;
      const uint16_t* wsrc = (const uint16_t*)WS[c & 1];

      float xs[2];
#pragma unroll
      for (int mi = 0; mi < 2; mi++) xs[mi] = bf2f(X0[x0row[mi] + h]);

      short8 bfr[4];
#pragma unroll
      for (int ni = 0; ni < 4; ni++)
        bfr[ni] = *(const short8*)(wsrc + boff[ni]);   // B[n][k=quad*8+j]

      short8 afr[2];
#pragma unroll
      for (int mi = 0; mi < 2; mi++) {
        uint4v w = *(const uint4v*)(xk16 + akoff[mi] + k2);  // 8 bf16 of xk
        const float s = xs[mi];
        uint32_t rr[4];
#pragma unroll
        for (int t = 0; t < 4; t++) {
          uint32_t wv = (t == 0) ? w.x : (t == 1) ? w.y : (t == 2) ? w.z : w.w;
          float lo = __uint_as_float(wv << 16) * s;          // even k
          float hi = __uint_as_float(wv & 0xffff0000u) * s;  // odd k
          rr[t] = __builtin_amdgcn_perm(__float_as_uint(hi), __float_as_uint(lo),
                                        0x07060302u);        // truncating pack
        }
        uint4v av = {rr[0], rr[1], rr[2], rr[3]};
        afr[mi] = __builtin_bit_cast(short8, av);            // A[m=l16][k=quad*8+j]
      }

#pragma unroll
      for (int mi = 0; mi < 2; mi++)
#pragma unroll
        for (int ni = 0; ni < 4; ni++)
          acc[mi][ni] = __builtin_amdgcn_mfma_f32_16x16x32_bf16(
              afr[mi], bfr[ni], acc[mi][ni], 0, 0, 0);
    } // chunk loop

    __syncthreads();  // all reads done before XK overwrite

    // ---- epilogue: bias + relu ; d-sum -> out ; xk handoff ----
    const float* bp = (L == 0) ? bias0 : ((L == 1) ? bias1 : bias2);
    float bv[4];
#pragma unroll
    for (int ni = 0; ni < 4; ni++) bv[ni] = bp[wn + ni * 16 + l16];

    // C/D layout: D[m = quad*4+reg][n = l16]; m-tile rows = 16 d's of batch bl
    if (L == 2 || wn == 64) {            // direct-output columns
#pragma unroll
      for (int mi = 0; mi < 2; mi++) {
        const int bl = mtb + mi;
#pragma unroll
        for (int ni = 0; ni < 4; ni++) {
          float sacc = 0.f;
#pragma unroll
          for (int r = 0; r < 4; r++) sacc += fmaxf(acc[mi][ni][r] + bv[ni], 0.f);
          sacc += __shfl_xor(sacc, 16);  // reduce over quad -> sum over 16 d
          sacc += __shfl_xor(sacc, 32);
          if (quad == 0) {
            // concat: L0 s64:128 -> 0:64 ; L1 s64:128 -> 64:128 ; L2 s -> 128:256
            int col = (L == 2) ? (128 + wn + ni * 16 + l16) : (L * 64 + ni * 16 + l16);
            out[(size_t)(bbase + bl) * 256 + col] = sacc;
          }
        }
      }
    }
    if (L < 2 && wn == 0) {              // xk = relu(z)[:, :64]  (waves 0,1: m 0..63)
#pragma unroll
      for (int mi = 0; mi < 2; mi++)
#pragma unroll
        for (int ni = 0; ni < 4; ni++)
#pragma unroll
          for (int r = 0; r < 4; r++) {
            int m = wm + mi * 16 + quad * 4 + r;
            int k = ni * 16 + l16;
            float z = fmaxf(acc[mi][ni][r] + bv[ni], 0.f);
            XK[m * XROW + k] = f2bf(z);
          }
    }
    // next layer's first __syncthreads orders XK writes before formation reads
  } // layer loop
}

extern "C" void kernel_launch(void* const* d_in, const int* in_sizes, int n_in,
                              void* d_out, int out_size, void* d_ws, size_t ws_size,
                              hipStream_t stream) {
  (void)in_sizes; (void)n_in; (void)out_size; (void)ws_size;
  const float* x  = (const float*)d_in[0];
  const float* w0 = (const float*)d_in[1];
  const float* b0 = (const float*)d_in[2];
  const float* w1 = (const float*)d_in[3];
  const float* b1 = (const float*)d_in[4];
  const float* w2 = (const float*)d_in[5];
  const float* b2 = (const float*)d_in[6];
  uint16_t* wblk  = (uint16_t*)d_ws;   // 234 * 5120 * 2 = 2,396,160 B

  cin_prepass<<<TOTCHUNK, 256, 0, stream>>>(w0, w1, w2, wblk);
  cin_main<<<512, 256, 0, stream>>>(x, b0, b1, b2, wblk, (float*)d_out);
}